// Round 8
// baseline (411.443 us; speedup 1.0000x reference)
//
#include <hip/hip_runtime.h>
#include <hip/hip_bf16.h>

#define N_NODES 50000
#define N_EDGES 800000
#define ETOT (N_EDGES + N_NODES)
#define N_GRAPHS 64
#define HEADS 4
#define IN_CH 128
#define HID 64
#define F1 256  // HEADS*HID
#define OUT_CH 32
#define F2 128  // HEADS*OUT_CH
#define POOL_SPLITS 16
#define SCAN_B 256
#define SCAN_NB ((N_NODES + SCAN_B - 1) / SCAN_B)  // 196

typedef unsigned short ushortT;
typedef unsigned int uintT;
typedef short v8s __attribute__((ext_vector_type(8)));
typedef float v4f __attribute__((ext_vector_type(4)));

__device__ __forceinline__ ushortT f2bf(float f) {
    union { float f; unsigned int i; } v; v.f = f;
    unsigned int x = v.i;
    unsigned int r = (x + 0x7fffu + ((x >> 16) & 1u)) >> 16;  // RNE
    return (ushortT)r;
}
__device__ __forceinline__ float bf_lo(uintT w) {
    union { unsigned int i; float f; } v; v.i = w << 16; return v.f;
}
__device__ __forceinline__ float bf_hi(uintT w) {
    union { unsigned int i; float f; } v; v.i = w & 0xffff0000u; return v.f;
}

// ---- CSR build over dst (shared by both GAT layers) ----
__global__ void k_count(const int* __restrict__ ei, int* __restrict__ counts) {
    int e = blockIdx.x * blockDim.x + threadIdx.x;
    if (e >= ETOT) return;
    int dst = (e < N_EDGES) ? ei[N_EDGES + e] : (e - N_EDGES);
    atomicAdd(&counts[dst], 1);
}

// ---- parallel 3-phase exclusive scan ----
__global__ void k_scan1(const int* __restrict__ counts, int* __restrict__ offs,
                        int* __restrict__ bsum) {
    __shared__ int sh[SCAN_B];
    int b = blockIdx.x, t = threadIdx.x;
    int i = b * SCAN_B + t;
    int v = (i < N_NODES) ? counts[i] : 0;
    sh[t] = v;
    __syncthreads();
    for (int o = 1; o < SCAN_B; o <<= 1) {
        int add = (t >= o) ? sh[t - o] : 0;
        __syncthreads();
        sh[t] += add;
        __syncthreads();
    }
    if (i < N_NODES) offs[i] = sh[t] - v;
    if (t == SCAN_B - 1) bsum[b] = sh[t];
}

__global__ void k_scan2(const int* __restrict__ bsum, int* __restrict__ bbase,
                        int* __restrict__ offs) {
    __shared__ int sh[SCAN_B];
    int t = threadIdx.x;
    int v = (t < SCAN_NB) ? bsum[t] : 0;
    sh[t] = v;
    __syncthreads();
    for (int o = 1; o < SCAN_B; o <<= 1) {
        int add = (t >= o) ? sh[t - o] : 0;
        __syncthreads();
        sh[t] += add;
        __syncthreads();
    }
    if (t < SCAN_NB) bbase[t] = sh[t] - v;
    if (t == SCAN_B - 1) offs[N_NODES] = sh[t];
}

__global__ void k_scan3(int* __restrict__ offs, const int* __restrict__ bbase) {
    int i = blockIdx.x * SCAN_B + threadIdx.x;
    if (i < N_NODES) offs[i] += bbase[blockIdx.x];
}

__global__ void k_scatter(const int* __restrict__ ei, const int* __restrict__ offsets,
                          int* __restrict__ cursor, int* __restrict__ csr_src) {
    int e = blockIdx.x * blockDim.x + threadIdx.x;
    if (e >= ETOT) return;
    int src, dst;
    if (e < N_EDGES) { src = ei[e]; dst = ei[N_EDGES + e]; }
    else             { src = dst = e - N_EDGES; }
    int pos = offsets[dst] + atomicAdd(&cursor[dst], 1);
    csr_src[pos] = src;
}

// ---- pack W (fp32 [K][N]) into bf16 B-fragment order for 16x16x32 MFMA ----
template <int FIN, int FOUT>
__global__ void k_packW(const float* __restrict__ W, ushortT* __restrict__ pW) {
    constexpr int KC = FIN / 32;
    int tid = blockIdx.x * blockDim.x + threadIdx.x;
    if (tid >= FIN * FOUT / 8) return;
    int lane = tid & 63;
    int g = tid >> 6;
    int kc = g % KC, nt = g / KC;
    int n = nt * 16 + (lane & 15);
    int kbase = kc * 32 + (lane >> 4) * 8;
    union { uint4 q; ushortT u[8]; } pk;
#pragma unroll
    for (int j = 0; j < 8; j++) pk.u[j] = f2bf(W[(kbase + j) * FOUT + n]);
    ((uint4*)pW)[tid] = pk.q;
}

// ---- MFMA GEMM: out[r][n] = sum_k A[r][k]*W[k][n], bf16 out ----
template <int FIN, int FOUT, bool ABF16>
__global__ __launch_bounds__(256) void k_gemm_mfma(const void* __restrict__ A,
                                                   const uint4* __restrict__ Wp,
                                                   ushortT* __restrict__ out, int nrows) {
    constexpr int KC = FIN / 32;
    constexpr int NT = FOUT / 16;
    __shared__ uintT lW[FIN * FOUT / 2];
    int tid = threadIdx.x;
    uint4* lW4 = (uint4*)lW;
    for (int i = tid; i < FIN * FOUT * 2 / 16; i += 256) lW4[i] = Wp[i];
    __syncthreads();

    int wave = tid >> 6, lane = tid & 63;
    long row0 = (long)blockIdx.x * 64 + wave * 16;
    if (row0 >= nrows) return;  // wave-uniform (nrows % 16 == 0)
    int m = lane & 15, b = lane >> 4;

    v8s afrag[KC];
    if (ABF16) {
        const ushortT* Ab = (const ushortT*)A;
#pragma unroll
        for (int kc = 0; kc < KC; kc++) {
            union { v8s v; uint4 q; } u;
            u.q = *(const uint4*)(Ab + (row0 + m) * FIN + kc * 32 + b * 8);
            afrag[kc] = u.v;
        }
    } else {
        const float* Af = (const float*)A;
#pragma unroll
        for (int kc = 0; kc < KC; kc++) {
            union { v8s v; ushortT u[8]; } u;
            const float* p = Af + (row0 + m) * FIN + kc * 32 + b * 8;
#pragma unroll
            for (int j = 0; j < 8; j++) u.u[j] = f2bf(p[j]);
            afrag[kc] = u.v;
        }
    }

    const ushortT* lWs = (const ushortT*)lW;
#pragma unroll
    for (int nt = 0; nt < NT; nt++) {
        v4f c = {0.f, 0.f, 0.f, 0.f};
#pragma unroll
        for (int kc = 0; kc < KC; kc++) {
            union { v8s v; uint4 q; } bu;
            bu.q = *(const uint4*)(lWs + ((nt * KC + kc) * 64 + lane) * 8);
            c = __builtin_amdgcn_mfma_f32_16x16x32_bf16(afrag[kc], bu.v, c, 0, 0, 0);
        }
        long r = row0 + b * 4;
        int col = nt * 16 + m;
#pragma unroll
        for (int reg = 0; reg < 4; reg++)
            out[(r + reg) * FOUT + col] = f2bf(c[reg]);
    }
}

// ---- per-node per-head attention terms s,d (bf16 h input) ----
template <int H, int C>
__global__ void k_sd(const ushortT* __restrict__ hb, const float* __restrict__ asrc,
                     const float* __restrict__ adst,
                     float* __restrict__ s, float* __restrict__ d) {
    int tid = blockIdx.x * blockDim.x + threadIdx.x;
    if (tid >= N_NODES * H) return;
    int n = tid / H, h = tid - n * H;
    const uintT* row = (const uintT*)(hb + (long)n * (H * C) + h * C);
    float ss = 0.f, dd = 0.f;
#pragma unroll 4
    for (int c2 = 0; c2 < C / 2; c2++) {
        uintT w = row[c2];
        float v0 = bf_lo(w), v1 = bf_hi(w);
        ss += v0 * asrc[h * C + 2 * c2] + v1 * asrc[h * C + 2 * c2 + 1];
        dd += v0 * adst[h * C + 2 * c2] + v1 * adst[h * C + 2 * c2 + 1];
    }
    s[tid] = ss; d[tid] = dd;
}

// ---- fused segment-softmax + aggregation: wave-autonomous ----
// One node per WAVE (WPB waves/block), zero LDS, zero barriers. Per 16-edge
// chunk: lane t computes exp for (edge t>>2, head t&3); accumulation pulls
// (ex, src) from lane (i<<2)|h via __shfl. exp once per (edge,head); no max
// pass (|e| <~ 6 -> fp32-safe; alpha mathematically identical).
template <int H, int C, int VEC, bool OUT_BF16, int WPB>
__global__ __launch_bounds__(64 * WPB) void k_agg(
        const ushortT* __restrict__ hb, const float* __restrict__ s,
        const float* __restrict__ d, const int* __restrict__ offsets,
        const int* __restrict__ csr_src, const float* __restrict__ bias,
        void* __restrict__ xout) {
    static_assert(H == 4, "H=4 assumed");
    constexpr int F = H * C;
    constexpr int TPN = F / VEC;
    static_assert(TPN == 64, "one wave per node");
    int wv = threadIdx.x >> 6;
    int n = blockIdx.x * WPB + wv;
    if (n >= N_NODES) return;
    int t = threadIdx.x & 63;
    int h = t / (C / VEC);        // accumulation head (= t>>4 for both layers)
    int hp = t & 3;               // exp-phase head
    int beg = offsets[n], end = offsets[n + 1];
    float dn = d[n * H + hp];

    float sumex = 0.f;
    float acc[VEC];
#pragma unroll
    for (int j = 0; j < VEC; j++) acc[j] = 0.f;

    const uint2* hb2 = (const uint2*)hb;
    const uintT* hb1 = (const uintT*)hb;

    for (int base = beg; base < end; base += 16) {
        int cnt16 = min(16, end - base);
        int i16 = t >> 2;
        int idx = base + i16;
        int sn_e = csr_src[min(idx, end - 1)];
        float e = s[sn_e * H + hp] + dn;
        e = e > 0.f ? e : 0.2f * e;
        float ex = (i16 < cnt16) ? __expf(e) : 0.f;
#pragma unroll 4
        for (int i = 0; i < cnt16; i++) {
            int sl = (i << 2) | h;
            float exi = __shfl(ex, sl, 64);
            int sni = __shfl(sn_e, sl, 64);
            sumex += exi;
            if (VEC == 4) {
                uint2 w = hb2[(long)sni * TPN + t];
                acc[0] += exi * bf_lo(w.x);
                acc[1] += exi * bf_hi(w.x);
                acc[2] += exi * bf_lo(w.y);
                acc[3] += exi * bf_hi(w.y);
            } else {
                uintT w = hb1[(long)sni * TPN + t];
                acc[0] += exi * bf_lo(w);
                acc[1] += exi * bf_hi(w);
            }
        }
    }
    float inv = 1.f / (sumex + 1e-16f);
    float o[VEC];
#pragma unroll
    for (int j = 0; j < VEC; j++)
        o[j] = fmaxf(acc[j] * inv + bias[t * VEC + j], 0.f);
    if (OUT_BF16) {
        if (VEC == 4) {
            uint2 pk;
            pk.x = (uintT)f2bf(o[0]) | ((uintT)f2bf(o[1]) << 16);
            pk.y = (uintT)f2bf(o[2]) | ((uintT)f2bf(o[3]) << 16);
            ((uint2*)xout)[(long)n * TPN + t] = pk;
        } else {
            uintT pk = (uintT)f2bf(o[0]) | ((uintT)f2bf(o[1]) << 16);
            ((uintT*)xout)[(long)n * TPN + t] = pk;
        }
    } else {
        float* xo = (float*)xout;
#pragma unroll
        for (int j = 0; j < VEC; j++) xo[(long)n * F + t * VEC + j] = o[j];
    }
}

// ---- graph boundaries via binary search on sorted batch ----
__global__ void k_bounds(const int* __restrict__ batch, int* __restrict__ bounds) {
    int g = threadIdx.x;
    if (g > N_GRAPHS) return;
    int lo = 0, hi = N_NODES;
    while (lo < hi) {
        int mid = (lo + hi) >> 1;
        if (batch[mid] < g) lo = mid + 1; else hi = mid;
    }
    bounds[g] = lo;
}

// ---- pool partials: block (g,s) sums a contiguous node slice, no atomics ----
__global__ void k_pool_partial(const float* __restrict__ x3, const int* __restrict__ bounds,
                               float* __restrict__ partial) {
    int g = blockIdx.x, s = blockIdx.y;
    int t = threadIdx.x;
    int n0 = bounds[g], n1 = bounds[g + 1];
    int len = n1 - n0;
    int a = n0 + (int)((long)len * s / POOL_SPLITS);
    int b = n0 + (int)((long)len * (s + 1) / POOL_SPLITS);
    float acc = 0.f;
    for (int n = a; n < b; n++) acc += x3[(long)n * F2 + t];
    partial[((long)g * POOL_SPLITS + s) * F2 + t] = acc;
}

// ---- head: block per graph — reduce partials, mean, logits, softmax ----
__global__ void k_head(const float* __restrict__ partial, const int* __restrict__ bounds,
                       const float* __restrict__ Wout, const float* __restrict__ bout,
                       float* __restrict__ out) {
    __shared__ float red0[F2], red1[F2];
    int g = blockIdx.x;
    int t = threadIdx.x;
    int cntN = bounds[g + 1] - bounds[g];
    float cnt = fmaxf((float)cntN, 1.0f);
    float sum = 0.f;
    for (int s = 0; s < POOL_SPLITS; s++)
        sum += partial[((long)g * POOL_SPLITS + s) * F2 + t];
    float p = sum / cnt;
    red0[t] = p * Wout[t * 2 + 0];
    red1[t] = p * Wout[t * 2 + 1];
    __syncthreads();
    for (int off = F2 / 2; off > 0; off >>= 1) {
        if (t < off) { red0[t] += red0[t + off]; red1[t] += red1[t + off]; }
        __syncthreads();
    }
    if (t == 0) {
        float l0 = red0[0] + bout[0];
        float l1 = red1[0] + bout[1];
        float m = fmaxf(l0, l1);
        float e0 = __expf(l0 - m), e1 = __expf(l1 - m);
        float inv = 1.f / (e0 + e1);
        out[g * 2 + 0] = e0 * inv;
        out[g * 2 + 1] = e1 * inv;
    }
}

extern "C" void kernel_launch(void* const* d_in, const int* in_sizes, int n_in,
                              void* d_out, int out_size, void* d_ws, size_t ws_size,
                              hipStream_t stream) {
    const float* x     = (const float*)d_in[0];
    const int*   ei    = (const int*)d_in[1];
    const int*   batch = (const int*)d_in[2];
    const float* W1    = (const float*)d_in[3];
    const float* asrc1 = (const float*)d_in[4];
    const float* adst1 = (const float*)d_in[5];
    const float* b1    = (const float*)d_in[6];
    const float* W2    = (const float*)d_in[7];
    const float* asrc2 = (const float*)d_in[8];
    const float* adst2 = (const float*)d_in[9];
    const float* b2    = (const float*)d_in[10];
    const float* Wout  = (const float*)d_in[11];
    const float* bout  = (const float*)d_in[12];

    char* ws = (char*)d_ws;
    size_t off = 0;
    auto alloc = [&](size_t bytes) -> void* {
        void* p = ws + off;
        off += (bytes + 255) / 256 * 256;
        return p;
    };
    ushortT* u_h   = (ushortT*)alloc(sizeof(ushortT) * (size_t)N_NODES * F1);
    ushortT* u_x1  = (ushortT*)alloc(sizeof(ushortT) * (size_t)N_NODES * F1);
    float*   f_x2  = (float*)alloc(sizeof(float) * (size_t)N_NODES * F2);
    float*   f_s   = (float*)alloc(sizeof(float) * (size_t)N_NODES * HEADS);
    float*   f_d   = (float*)alloc(sizeof(float) * (size_t)N_NODES * HEADS);
    int*     i_cnt = (int*)alloc(sizeof(int) * (size_t)N_NODES);
    int*     i_off = (int*)alloc(sizeof(int) * (size_t)(N_NODES + 1));
    int*     i_cur = (int*)alloc(sizeof(int) * (size_t)N_NODES);
    int*     i_csr = (int*)alloc(sizeof(int) * (size_t)ETOT);
    int*     i_bnd = (int*)alloc(sizeof(int) * (size_t)(N_GRAPHS + 1));
    int*     i_bs  = (int*)alloc(sizeof(int) * SCAN_NB);
    int*     i_bb  = (int*)alloc(sizeof(int) * SCAN_NB);
    float*   f_prt = (float*)alloc(sizeof(float) * (size_t)N_GRAPHS * POOL_SPLITS * F2);
    ushortT* pW1   = (ushortT*)alloc(sizeof(ushortT) * IN_CH * F1);
    ushortT* pW2   = (ushortT*)alloc(sizeof(ushortT) * F1 * F2);
    (void)ws_size; (void)in_sizes; (void)n_in; (void)out_size;

    hipMemsetAsync(i_cnt, 0, sizeof(int) * N_NODES, stream);
    hipMemsetAsync(i_cur, 0, sizeof(int) * N_NODES, stream);

    // CSR over dst (same for both layers); 3-phase parallel exclusive scan
    k_count<<<(ETOT + 255) / 256, 256, 0, stream>>>(ei, i_cnt);
    k_scan1<<<SCAN_NB, SCAN_B, 0, stream>>>(i_cnt, i_off, i_bs);
    k_scan2<<<1, SCAN_B, 0, stream>>>(i_bs, i_bb, i_off);
    k_scan3<<<SCAN_NB, SCAN_B, 0, stream>>>(i_off, i_bb);
    k_scatter<<<(ETOT + 255) / 256, 256, 0, stream>>>(ei, i_off, i_cur, i_csr);

    // Pack weights into MFMA B-fragment order (bf16)
    k_packW<IN_CH, F1><<<(IN_CH * F1 / 8 + 255) / 256, 256, 0, stream>>>(W1, pW1);
    k_packW<F1, F2><<<(F1 * F2 / 8 + 255) / 256, 256, 0, stream>>>(W2, pW2);

    int gemm_grid = (N_NODES + 63) / 64;
    int agg_grid = (N_NODES + 3) / 4;

    // Layer 1
    k_gemm_mfma<IN_CH, F1, false><<<gemm_grid, 256, 0, stream>>>(x, (const uint4*)pW1, u_h, N_NODES);
    k_sd<HEADS, HID><<<(N_NODES * HEADS + 255) / 256, 256, 0, stream>>>(u_h, asrc1, adst1, f_s, f_d);
    k_agg<HEADS, HID, 4, true, 4><<<agg_grid, 256, 0, stream>>>(u_h, f_s, f_d, i_off, i_csr, b1, u_x1);

    // Layer 2
    k_gemm_mfma<F1, F2, true><<<gemm_grid, 256, 0, stream>>>(u_x1, (const uint4*)pW2, u_h, N_NODES);
    k_sd<HEADS, OUT_CH><<<(N_NODES * HEADS + 255) / 256, 256, 0, stream>>>(u_h, asrc2, adst2, f_s, f_d);
    k_agg<HEADS, OUT_CH, 2, false, 4><<<agg_grid, 256, 0, stream>>>(u_h, f_s, f_d, i_off, i_csr, b2, f_x2);

    // Pool + head (no atomics: batch is sorted -> contiguous graph ranges)
    k_bounds<<<1, N_GRAPHS + 1, 0, stream>>>(batch, i_bnd);
    dim3 pgrid(N_GRAPHS, POOL_SPLITS);
    k_pool_partial<<<pgrid, F2, 0, stream>>>(f_x2, i_bnd, f_prt);
    k_head<<<N_GRAPHS, F2, 0, stream>>>(f_prt, i_bnd, Wout, bout, (float*)d_out);
}

// Round 9
// 371.498 us; speedup vs baseline: 1.1075x; 1.1075x over previous
//
#include <hip/hip_runtime.h>
#include <hip/hip_bf16.h>

#define N_NODES 50000
#define N_EDGES 800000
#define ETOT (N_EDGES + N_NODES)
#define N_GRAPHS 64
#define HEADS 4
#define IN_CH 128
#define HID 64
#define F1 256  // HEADS*HID
#define OUT_CH 32
#define F2 128  // HEADS*OUT_CH
#define POOL_SPLITS 16
#define SCAN_B 256
#define SCAN_NB ((N_NODES + SCAN_B - 1) / SCAN_B)  // 196

typedef unsigned short ushortT;
typedef unsigned int uintT;
typedef short v8s __attribute__((ext_vector_type(8)));
typedef float v4f __attribute__((ext_vector_type(4)));

__device__ __forceinline__ ushortT f2bf(float f) {
    union { float f; unsigned int i; } v; v.f = f;
    unsigned int x = v.i;
    unsigned int r = (x + 0x7fffu + ((x >> 16) & 1u)) >> 16;  // RNE
    return (ushortT)r;
}
__device__ __forceinline__ float bf_lo(uintT w) {
    union { unsigned int i; float f; } v; v.i = w << 16; return v.f;
}
__device__ __forceinline__ float bf_hi(uintT w) {
    union { unsigned int i; float f; } v; v.i = w & 0xffff0000u; return v.f;
}

// ---- CSR build over dst (shared by both GAT layers) ----
__global__ void k_count(const int* __restrict__ ei, int* __restrict__ counts) {
    int e = blockIdx.x * blockDim.x + threadIdx.x;
    if (e >= ETOT) return;
    int dst = (e < N_EDGES) ? ei[N_EDGES + e] : (e - N_EDGES);
    atomicAdd(&counts[dst], 1);
}

// ---- parallel 3-phase exclusive scan ----
__global__ void k_scan1(const int* __restrict__ counts, int* __restrict__ offs,
                        int* __restrict__ bsum) {
    __shared__ int sh[SCAN_B];
    int b = blockIdx.x, t = threadIdx.x;
    int i = b * SCAN_B + t;
    int v = (i < N_NODES) ? counts[i] : 0;
    sh[t] = v;
    __syncthreads();
    for (int o = 1; o < SCAN_B; o <<= 1) {
        int add = (t >= o) ? sh[t - o] : 0;
        __syncthreads();
        sh[t] += add;
        __syncthreads();
    }
    if (i < N_NODES) offs[i] = sh[t] - v;
    if (t == SCAN_B - 1) bsum[b] = sh[t];
}

__global__ void k_scan2(const int* __restrict__ bsum, int* __restrict__ bbase,
                        int* __restrict__ offs) {
    __shared__ int sh[SCAN_B];
    int t = threadIdx.x;
    int v = (t < SCAN_NB) ? bsum[t] : 0;
    sh[t] = v;
    __syncthreads();
    for (int o = 1; o < SCAN_B; o <<= 1) {
        int add = (t >= o) ? sh[t - o] : 0;
        __syncthreads();
        sh[t] += add;
        __syncthreads();
    }
    if (t < SCAN_NB) bbase[t] = sh[t] - v;
    if (t == SCAN_B - 1) offs[N_NODES] = sh[t];
}

__global__ void k_scan3(int* __restrict__ offs, const int* __restrict__ bbase) {
    int i = blockIdx.x * SCAN_B + threadIdx.x;
    if (i < N_NODES) offs[i] += bbase[blockIdx.x];
}

__global__ void k_scatter(const int* __restrict__ ei, const int* __restrict__ offsets,
                          int* __restrict__ cursor, int* __restrict__ csr_src) {
    int e = blockIdx.x * blockDim.x + threadIdx.x;
    if (e >= ETOT) return;
    int src, dst;
    if (e < N_EDGES) { src = ei[e]; dst = ei[N_EDGES + e]; }
    else             { src = dst = e - N_EDGES; }
    int pos = offsets[dst] + atomicAdd(&cursor[dst], 1);
    csr_src[pos] = src;
}

// ---- pack W (fp32 [K][N]) into bf16 B-fragment order for 16x16x32 MFMA ----
template <int FIN, int FOUT>
__global__ void k_packW(const float* __restrict__ W, ushortT* __restrict__ pW) {
    constexpr int KC = FIN / 32;
    int tid = blockIdx.x * blockDim.x + threadIdx.x;
    if (tid >= FIN * FOUT / 8) return;
    int lane = tid & 63;
    int g = tid >> 6;
    int kc = g % KC, nt = g / KC;
    int n = nt * 16 + (lane & 15);
    int kbase = kc * 32 + (lane >> 4) * 8;
    union { uint4 q; ushortT u[8]; } pk;
#pragma unroll
    for (int j = 0; j < 8; j++) pk.u[j] = f2bf(W[(kbase + j) * FOUT + n]);
    ((uint4*)pW)[tid] = pk.q;
}

// ---- MFMA GEMM: out[r][n] = sum_k A[r][k]*W[k][n], bf16 out ----
template <int FIN, int FOUT, bool ABF16>
__global__ __launch_bounds__(256) void k_gemm_mfma(const void* __restrict__ A,
                                                   const uint4* __restrict__ Wp,
                                                   ushortT* __restrict__ out, int nrows) {
    constexpr int KC = FIN / 32;
    constexpr int NT = FOUT / 16;
    __shared__ uintT lW[FIN * FOUT / 2];
    int tid = threadIdx.x;
    uint4* lW4 = (uint4*)lW;
    for (int i = tid; i < FIN * FOUT * 2 / 16; i += 256) lW4[i] = Wp[i];
    __syncthreads();

    int wave = tid >> 6, lane = tid & 63;
    long row0 = (long)blockIdx.x * 64 + wave * 16;
    if (row0 >= nrows) return;  // wave-uniform (nrows % 16 == 0)
    int m = lane & 15, b = lane >> 4;

    v8s afrag[KC];
    if (ABF16) {
        const ushortT* Ab = (const ushortT*)A;
#pragma unroll
        for (int kc = 0; kc < KC; kc++) {
            union { v8s v; uint4 q; } u;
            u.q = *(const uint4*)(Ab + (row0 + m) * FIN + kc * 32 + b * 8);
            afrag[kc] = u.v;
        }
    } else {
        const float* Af = (const float*)A;
#pragma unroll
        for (int kc = 0; kc < KC; kc++) {
            union { v8s v; ushortT u[8]; } u;
            const float* p = Af + (row0 + m) * FIN + kc * 32 + b * 8;
#pragma unroll
            for (int j = 0; j < 8; j++) u.u[j] = f2bf(p[j]);
            afrag[kc] = u.v;
        }
    }

    const ushortT* lWs = (const ushortT*)lW;
#pragma unroll
    for (int nt = 0; nt < NT; nt++) {
        v4f c = {0.f, 0.f, 0.f, 0.f};
#pragma unroll
        for (int kc = 0; kc < KC; kc++) {
            union { v8s v; uint4 q; } bu;
            bu.q = *(const uint4*)(lWs + ((nt * KC + kc) * 64 + lane) * 8);
            c = __builtin_amdgcn_mfma_f32_16x16x32_bf16(afrag[kc], bu.v, c, 0, 0, 0);
        }
        long r = row0 + b * 4;
        int col = nt * 16 + m;
#pragma unroll
        for (int reg = 0; reg < 4; reg++)
            out[(r + reg) * FOUT + col] = f2bf(c[reg]);
    }
}

// ---- per-node per-head attention terms s,d (bf16 h input) ----
template <int H, int C>
__global__ void k_sd(const ushortT* __restrict__ hb, const float* __restrict__ asrc,
                     const float* __restrict__ adst,
                     float* __restrict__ s, float* __restrict__ d) {
    int tid = blockIdx.x * blockDim.x + threadIdx.x;
    if (tid >= N_NODES * H) return;
    int n = tid / H, h = tid - n * H;
    const uintT* row = (const uintT*)(hb + (long)n * (H * C) + h * C);
    float ss = 0.f, dd = 0.f;
#pragma unroll 4
    for (int c2 = 0; c2 < C / 2; c2++) {
        uintT w = row[c2];
        float v0 = bf_lo(w), v1 = bf_hi(w);
        ss += v0 * asrc[h * C + 2 * c2] + v1 * asrc[h * C + 2 * c2 + 1];
        dd += v0 * adst[h * C + 2 * c2] + v1 * adst[h * C + 2 * c2 + 1];
    }
    s[tid] = ss; d[tid] = dd;
}

// ---- fused segment-softmax + aggregation: one node per wave, NO barriers ----
// WPB waves/block, each wave owns node n and a private LDS slice. Phase 1:
// lane i stages edge base+i (coalesced csr_src load, float4 s-gather, 4 exps,
// b128 LDS write). Intra-wave LDS visibility needs only s_waitcnt lgkmcnt(0)
// (lockstep wave) -- no __syncthreads, so waves run independently. Phase 2:
// broadcast LDS reads + vectorized bf16 gather. exp once per (edge,head); no
// max pass (|e| <~ 6: fp32-safe; alpha mathematically identical).
template <int H, int C, int VEC, bool OUT_BF16, int WPB, int CHUNK>
__global__ __launch_bounds__(64 * WPB) void k_agg(
        const ushortT* __restrict__ hb, const float* __restrict__ s,
        const float* __restrict__ d, const int* __restrict__ offsets,
        const int* __restrict__ csr_src, const float* __restrict__ bias,
        void* __restrict__ xout) {
    static_assert(H == 4, "H=4 assumed");
    constexpr int F = H * C;
    constexpr int TPN = F / VEC;
    static_assert(TPN == 64, "one wave per node");
    __shared__ int lsrc[WPB][CHUNK];
    __shared__ float lex[WPB][CHUNK * H];
    int wv = threadIdx.x >> 6;
    int n = blockIdx.x * WPB + wv;
    if (n >= N_NODES) return;
    int t = threadIdx.x & 63;
    int h = t / (C / VEC);
    int beg = offsets[n], end = offsets[n + 1];
    // wave-uniform d values (scalar loads)
    float dn0 = d[n * H + 0], dn1 = d[n * H + 1];
    float dn2 = d[n * H + 2], dn3 = d[n * H + 3];

    float sumex = 0.f;
    float acc[VEC];
#pragma unroll
    for (int j = 0; j < VEC; j++) acc[j] = 0.f;

    const uint2* hb2 = (const uint2*)hb;
    const uintT* hb1 = (const uintT*)hb;

    for (int base = beg; base < end; base += CHUNK) {
        int cnt = min(CHUNK, end - base);
        // phase 1: stage src ids + per-head exp into this wave's LDS slice
        for (int i = t; i < cnt; i += 64) {
            int sn = csr_src[base + i];
            lsrc[wv][i] = sn;
            float4 sv = *(const float4*)(s + sn * 4);
            float e0 = sv.x + dn0; e0 = e0 > 0.f ? e0 : 0.2f * e0;
            float e1 = sv.y + dn1; e1 = e1 > 0.f ? e1 : 0.2f * e1;
            float e2 = sv.z + dn2; e2 = e2 > 0.f ? e2 : 0.2f * e2;
            float e3 = sv.w + dn3; e3 = e3 > 0.f ? e3 : 0.2f * e3;
            float4 exv = { __expf(e0), __expf(e1), __expf(e2), __expf(e3) };
            *(float4*)&lex[wv][i * 4] = exv;
        }
        // intra-wave LDS write->read ordering (no block barrier needed)
        asm volatile("s_waitcnt lgkmcnt(0)" ::: "memory");
        // phase 2: accumulate
#pragma unroll 4
        for (int i = 0; i < cnt; i++) {
            float ex = lex[wv][i * H + h];
            int sn = lsrc[wv][i];
            sumex += ex;
            if (VEC == 4) {
                uint2 w = hb2[(long)sn * TPN + t];
                acc[0] += ex * bf_lo(w.x);
                acc[1] += ex * bf_hi(w.x);
                acc[2] += ex * bf_lo(w.y);
                acc[3] += ex * bf_hi(w.y);
            } else {
                uintT w = hb1[(long)sn * TPN + t];
                acc[0] += ex * bf_lo(w);
                acc[1] += ex * bf_hi(w);
            }
        }
        // keep next chunk's LDS writes from overtaking this chunk's reads
        asm volatile("" ::: "memory");
    }
    float inv = 1.f / (sumex + 1e-16f);
    float o[VEC];
#pragma unroll
    for (int j = 0; j < VEC; j++)
        o[j] = fmaxf(acc[j] * inv + bias[t * VEC + j], 0.f);
    if (OUT_BF16) {
        if (VEC == 4) {
            uint2 pk;
            pk.x = (uintT)f2bf(o[0]) | ((uintT)f2bf(o[1]) << 16);
            pk.y = (uintT)f2bf(o[2]) | ((uintT)f2bf(o[3]) << 16);
            ((uint2*)xout)[(long)n * TPN + t] = pk;
        } else {
            uintT pk = (uintT)f2bf(o[0]) | ((uintT)f2bf(o[1]) << 16);
            ((uintT*)xout)[(long)n * TPN + t] = pk;
        }
    } else {
        float* xo = (float*)xout;
#pragma unroll
        for (int j = 0; j < VEC; j++) xo[(long)n * F + t * VEC + j] = o[j];
    }
}

// ---- graph boundaries via binary search on sorted batch ----
__global__ void k_bounds(const int* __restrict__ batch, int* __restrict__ bounds) {
    int g = threadIdx.x;
    if (g > N_GRAPHS) return;
    int lo = 0, hi = N_NODES;
    while (lo < hi) {
        int mid = (lo + hi) >> 1;
        if (batch[mid] < g) lo = mid + 1; else hi = mid;
    }
    bounds[g] = lo;
}

// ---- pool partials: block (g,s) sums a contiguous node slice, no atomics ----
__global__ void k_pool_partial(const float* __restrict__ x3, const int* __restrict__ bounds,
                               float* __restrict__ partial) {
    int g = blockIdx.x, s = blockIdx.y;
    int t = threadIdx.x;
    int n0 = bounds[g], n1 = bounds[g + 1];
    int len = n1 - n0;
    int a = n0 + (int)((long)len * s / POOL_SPLITS);
    int b = n0 + (int)((long)len * (s + 1) / POOL_SPLITS);
    float acc = 0.f;
    for (int n = a; n < b; n++) acc += x3[(long)n * F2 + t];
    partial[((long)g * POOL_SPLITS + s) * F2 + t] = acc;
}

// ---- head: block per graph — reduce partials, mean, logits, softmax ----
__global__ void k_head(const float* __restrict__ partial, const int* __restrict__ bounds,
                       const float* __restrict__ Wout, const float* __restrict__ bout,
                       float* __restrict__ out) {
    __shared__ float red0[F2], red1[F2];
    int g = blockIdx.x;
    int t = threadIdx.x;
    int cntN = bounds[g + 1] - bounds[g];
    float cnt = fmaxf((float)cntN, 1.0f);
    float sum = 0.f;
    for (int s = 0; s < POOL_SPLITS; s++)
        sum += partial[((long)g * POOL_SPLITS + s) * F2 + t];
    float p = sum / cnt;
    red0[t] = p * Wout[t * 2 + 0];
    red1[t] = p * Wout[t * 2 + 1];
    __syncthreads();
    for (int off = F2 / 2; off > 0; off >>= 1) {
        if (t < off) { red0[t] += red0[t + off]; red1[t] += red1[t + off]; }
        __syncthreads();
    }
    if (t == 0) {
        float l0 = red0[0] + bout[0];
        float l1 = red1[0] + bout[1];
        float m = fmaxf(l0, l1);
        float e0 = __expf(l0 - m), e1 = __expf(l1 - m);
        float inv = 1.f / (e0 + e1);
        out[g * 2 + 0] = e0 * inv;
        out[g * 2 + 1] = e1 * inv;
    }
}

extern "C" void kernel_launch(void* const* d_in, const int* in_sizes, int n_in,
                              void* d_out, int out_size, void* d_ws, size_t ws_size,
                              hipStream_t stream) {
    const float* x     = (const float*)d_in[0];
    const int*   ei    = (const int*)d_in[1];
    const int*   batch = (const int*)d_in[2];
    const float* W1    = (const float*)d_in[3];
    const float* asrc1 = (const float*)d_in[4];
    const float* adst1 = (const float*)d_in[5];
    const float* b1    = (const float*)d_in[6];
    const float* W2    = (const float*)d_in[7];
    const float* asrc2 = (const float*)d_in[8];
    const float* adst2 = (const float*)d_in[9];
    const float* b2    = (const float*)d_in[10];
    const float* Wout  = (const float*)d_in[11];
    const float* bout  = (const float*)d_in[12];

    char* ws = (char*)d_ws;
    size_t off = 0;
    auto alloc = [&](size_t bytes) -> void* {
        void* p = ws + off;
        off += (bytes + 255) / 256 * 256;
        return p;
    };
    ushortT* u_h   = (ushortT*)alloc(sizeof(ushortT) * (size_t)N_NODES * F1);
    ushortT* u_x1  = (ushortT*)alloc(sizeof(ushortT) * (size_t)N_NODES * F1);
    float*   f_x2  = (float*)alloc(sizeof(float) * (size_t)N_NODES * F2);
    float*   f_s   = (float*)alloc(sizeof(float) * (size_t)N_NODES * HEADS);
    float*   f_d   = (float*)alloc(sizeof(float) * (size_t)N_NODES * HEADS);
    int*     i_cnt = (int*)alloc(sizeof(int) * (size_t)N_NODES);
    int*     i_off = (int*)alloc(sizeof(int) * (size_t)(N_NODES + 1));
    int*     i_cur = (int*)alloc(sizeof(int) * (size_t)N_NODES);
    int*     i_csr = (int*)alloc(sizeof(int) * (size_t)ETOT);
    int*     i_bnd = (int*)alloc(sizeof(int) * (size_t)(N_GRAPHS + 1));
    int*     i_bs  = (int*)alloc(sizeof(int) * SCAN_NB);
    int*     i_bb  = (int*)alloc(sizeof(int) * SCAN_NB);
    float*   f_prt = (float*)alloc(sizeof(float) * (size_t)N_GRAPHS * POOL_SPLITS * F2);
    ushortT* pW1   = (ushortT*)alloc(sizeof(ushortT) * IN_CH * F1);
    ushortT* pW2   = (ushortT*)alloc(sizeof(ushortT) * F1 * F2);
    (void)ws_size; (void)in_sizes; (void)n_in; (void)out_size;

    hipMemsetAsync(i_cnt, 0, sizeof(int) * N_NODES, stream);
    hipMemsetAsync(i_cur, 0, sizeof(int) * N_NODES, stream);

    // CSR over dst (same for both layers); 3-phase parallel exclusive scan
    k_count<<<(ETOT + 255) / 256, 256, 0, stream>>>(ei, i_cnt);
    k_scan1<<<SCAN_NB, SCAN_B, 0, stream>>>(i_cnt, i_off, i_bs);
    k_scan2<<<1, SCAN_B, 0, stream>>>(i_bs, i_bb, i_off);
    k_scan3<<<SCAN_NB, SCAN_B, 0, stream>>>(i_off, i_bb);
    k_scatter<<<(ETOT + 255) / 256, 256, 0, stream>>>(ei, i_off, i_cur, i_csr);

    // Pack weights into MFMA B-fragment order (bf16)
    k_packW<IN_CH, F1><<<(IN_CH * F1 / 8 + 255) / 256, 256, 0, stream>>>(W1, pW1);
    k_packW<F1, F2><<<(F1 * F2 / 8 + 255) / 256, 256, 0, stream>>>(W2, pW2);

    int gemm_grid = (N_NODES + 63) / 64;
    int agg_grid = (N_NODES + 3) / 4;

    // Layer 1
    k_gemm_mfma<IN_CH, F1, false><<<gemm_grid, 256, 0, stream>>>(x, (const uint4*)pW1, u_h, N_NODES);
    k_sd<HEADS, HID><<<(N_NODES * HEADS + 255) / 256, 256, 0, stream>>>(u_h, asrc1, adst1, f_s, f_d);
    k_agg<HEADS, HID, 4, true, 4, 128><<<agg_grid, 256, 0, stream>>>(u_h, f_s, f_d, i_off, i_csr, b1, u_x1);

    // Layer 2
    k_gemm_mfma<F1, F2, true><<<gemm_grid, 256, 0, stream>>>(u_x1, (const uint4*)pW2, u_h, N_NODES);
    k_sd<HEADS, OUT_CH><<<(N_NODES * HEADS + 255) / 256, 256, 0, stream>>>(u_h, asrc2, adst2, f_s, f_d);
    k_agg<HEADS, OUT_CH, 2, false, 4, 128><<<agg_grid, 256, 0, stream>>>(u_h, f_s, f_d, i_off, i_csr, b2, f_x2);

    // Pool + head (no atomics: batch is sorted -> contiguous graph ranges)
    k_bounds<<<1, N_GRAPHS + 1, 0, stream>>>(batch, i_bnd);
    dim3 pgrid(N_GRAPHS, POOL_SPLITS);
    k_pool_partial<<<pgrid, F2, 0, stream>>>(f_x2, i_bnd, f_prt);
    k_head<<<N_GRAPHS, F2, 0, stream>>>(f_prt, i_bnd, Wout, bout, (float*)d_out);
}